// Round 14
// baseline (188.994 us; speedup 1.0000x reference)
//
#include <hip/hip_runtime.h>
#include <math.h>

#define B_ 4
#define S_ 2048
#define D_ 512
#define H_ 8
#define HD_ 64
#define SZ_ (B_ * S_ * D_)
#define WSZ_ (D_ * D_)   // 262144
#define BSH_ (B_ * S_ * H_)

// 0.125 * log2(e): folds the 1/sqrt(64) score scale and exp->exp2 into Qh.
#define QSCALE_ 0.18033688011112042f

typedef _Float16 v4h __attribute__((ext_vector_type(4)));
typedef _Float16 v8h __attribute__((ext_vector_type(8)));
typedef float    v4f __attribute__((ext_vector_type(4)));

// Async global->LDS, 16B per lane. LDS dest must be wave-uniform base
// (HW adds lane*16); global source is per-lane.
__device__ __forceinline__ void gload16(const void* g, void* l) {
    __builtin_amdgcn_global_load_lds((__attribute__((address_space(1))) void*)g,
                                     (__attribute__((address_space(3))) void*)l,
                                     16, 0, 0);
}

__device__ __forceinline__ v8h pack8(v4f a, v4f b) {
    return __builtin_shufflevector(__builtin_convertvector(a, v4h),
                                   __builtin_convertvector(b, v4h),
                                   0, 1, 2, 3, 4, 5, 6, 7);
}

// ---------------------------------------------------------------------------
// W[k][n] fp32 -> 16KB swizzled f16 blocks, 128 n-rows x 64 k each.
// ---------------------------------------------------------------------------
__global__ __launch_bounds__(256) void wtrans_kernel(const float* __restrict__ Wq,
                                                     const float* __restrict__ Wo,
                                                     _Float16* __restrict__ Wt) {
    __shared__ float Ts[64][132];
    const int kc = blockIdx.x, nt = blockIdx.y, mat = blockIdx.z;
    const float* W = mat ? Wo : Wq;
    const int k0 = kc * 64, n0 = nt * 128;
    const int t = threadIdx.x;
#pragma unroll
    for (int i = 0; i < 8; i++) {
        int s2 = t + i * 256;
        int kk = s2 >> 5, nc = (s2 & 31) * 4;
        *(float4*)&Ts[kk][nc] = *(const float4*)&W[(size_t)(k0 + kk) * 512 + n0 + nc];
    }
    __syncthreads();
    _Float16* blk = Wt + (((size_t)mat * 4 + nt) * 8 + kc) * 8192;
#pragma unroll
    for (int i = 0; i < 4; i++) {
        int s2 = t + i * 256;
        int r = s2 >> 3, s = s2 & 7;
        int kl = (s ^ (r & 7)) * 8;
        v8h p;
#pragma unroll
        for (int j = 0; j < 8; j++) p[j] = (_Float16)Ts[kl + j][r];
        *(v8h*)&blk[r * 64 + s * 8] = p;
    }
}

// ---------------------------------------------------------------------------
// R20 proj (FROZEN): 2-phase single-barrier pipelined GEMM.
// ---------------------------------------------------------------------------
__global__ __launch_bounds__(256) void proj_mfma(const float* __restrict__ q,
                                                 const float* __restrict__ kin,
                                                 const float* __restrict__ v,
                                                 const _Float16* __restrict__ Wt,
                                                 const float* __restrict__ bq,
                                                 _Float16* __restrict__ Qh,
                                                 _Float16* __restrict__ Kh,
                                                 _Float16* __restrict__ VT) {
    __shared__ __align__(16) _Float16 As[2][8192];
    __shared__ __align__(16) _Float16 Bs[2][8192];
    const int blk = blockIdx.x;
    const int wl = (blk & 7) * 96 + (blk >> 3);
    const int z = wl >> 8;
    const int rem = wl & 255;
    const int mt = rem >> 2, nt = rem & 3;
    const int n0 = nt * 128, m0 = mt * 128;
    const float* X = (z == 0) ? q : ((z == 1) ? kin : v);
    const int t = threadIdx.x, lane = t & 63, w = t >> 6;
    const int wm = w >> 1, wn = w & 1;
    const int quad = lane >> 4, l16 = lane & 15;

    const float* Ap[4];
    int wofs[4];
#pragma unroll
    for (int i = 0; i < 4; i++) {
        int s2 = t + i * 256;
        int r = s2 >> 3, c = s2 & 7;
        Ap[i] = X + (size_t)(m0 + r) * 512 + c * 8;
        wofs[i] = r * 64 + ((c ^ (r & 7)) * 8);
    }
    const _Float16* Bb = Wt + ((size_t)nt * 8) * 8192 + w * 512 + lane * 8;

    v4f acc[4][4];
#pragma unroll
    for (int mi = 0; mi < 4; mi++)
#pragma unroll
        for (int ni = 0; ni < 4; ni++) acc[mi][ni] = (v4f)0.f;

    v4f a0[4], a1[4];
#pragma unroll
    for (int i = 0; i < 4; i++) {
        a0[i] = *(const v4f*)(Ap[i]);
        a1[i] = *(const v4f*)(Ap[i] + 4);
    }
#pragma unroll
    for (int i = 0; i < 4; i++) *(v8h*)&As[0][wofs[i]] = pack8(a0[i], a1[i]);
#pragma unroll
    for (int i = 0; i < 4; i++)
        gload16(Bb + i * 2048, &Bs[0][w * 512 + i * 2048]);
#pragma unroll
    for (int i = 0; i < 4; i++) {
        a0[i] = *(const v4f*)(Ap[i] + 64);
        a1[i] = *(const v4f*)(Ap[i] + 68);
    }
    __syncthreads();

    int cur = 0;
    for (int kc = 0; kc < 8; ++kc) {
        const int nxt = cur ^ 1;
        if (kc + 1 < 8) {
#pragma unroll
            for (int i = 0; i < 4; i++) *(v8h*)&As[nxt][wofs[i]] = pack8(a0[i], a1[i]);
#pragma unroll
            for (int i = 0; i < 4; i++)
                gload16(Bb + (kc + 1) * 8192 + i * 2048, &Bs[nxt][w * 512 + i * 2048]);
        }
        if (kc + 2 < 8) {
#pragma unroll
            for (int i = 0; i < 4; i++) {
                a0[i] = *(const v4f*)(Ap[i] + (kc + 2) * 64);
                a1[i] = *(const v4f*)(Ap[i] + (kc + 2) * 64 + 4);
            }
        }

#pragma unroll
        for (int ks = 0; ks < 2; ++ks) {
            const int sxx = (ks * 32 + quad * 8) ^ ((l16 & 7) * 8);
            v8h af[4], bf[4];
#pragma unroll
            for (int mi = 0; mi < 4; mi++)
                af[mi] = *(const v8h*)&As[cur][(wm * 64 + mi * 16 + l16) * 64 + sxx];
#pragma unroll
            for (int ni = 0; ni < 4; ni++)
                bf[ni] = *(const v8h*)&Bs[cur][(wn * 64 + ni * 16 + l16) * 64 + sxx];
#pragma unroll
            for (int mi = 0; mi < 4; mi++)
#pragma unroll
                for (int ni = 0; ni < 4; ni++)
                    acc[mi][ni] = __builtin_amdgcn_mfma_f32_16x16x32_f16(af[mi], bf[ni], acc[mi][ni], 0, 0, 0);
        }
        __syncthreads();
        cur = nxt;
    }

    if (z < 2) {
        _Float16* Y = z ? Kh : Qh;
        const float sc = z ? 1.f : QSCALE_;
#pragma unroll
        for (int mi = 0; mi < 4; mi++) {
            int mb = m0 + wm * 64 + mi * 16 + quad * 4;
#pragma unroll
            for (int ni = 0; ni < 4; ni++) {
                int n = n0 + wn * 64 + ni * 16 + l16;
                float bj = bq[n];
#pragma unroll
                for (int r = 0; r < 4; r++)
                    Y[(size_t)(mb + r) * 512 + n] = (_Float16)((acc[mi][ni][r] + bj) * sc);
            }
        }
    } else {
#pragma unroll
        for (int mi = 0; mi < 4; mi++) {
            int tile0 = (m0 & 2047) + wm * 64;
            int pos = tile0 + (mi >> 1) * 32 + quad * 8 + (mi & 1) * 4;
            int b = m0 >> 11;
#pragma unroll
            for (int ni = 0; ni < 4; ni++) {
                int n = n0 + wn * 64 + ni * 16 + l16;
                int h = n >> 6, dd = n & 63;
                float bj = bq[n];
                v4h pk;
#pragma unroll
                for (int r = 0; r < 4; r++) pk[r] = (_Float16)(acc[mi][ni][r] + bj);
                *(v4h*)&VT[(((size_t)b * H_ + h) * HD_ + dd) * S_ + pos] = pk;
            }
        }
    }
}

// ---------------------------------------------------------------------------
// R20 outproj (FROZEN): 2-phase single-barrier, both operands gload_lds dbuf.
// ---------------------------------------------------------------------------
__global__ __launch_bounds__(256) void outproj_mfma(const _Float16* __restrict__ Ah,
                                                    const _Float16* __restrict__ Wt,
                                                    const float* __restrict__ bo,
                                                    float* __restrict__ out) {
    __shared__ __align__(16) _Float16 As[2][8192];
    __shared__ __align__(16) _Float16 Bs[2][8192];
    const int blk = blockIdx.x;
    const int wl = (blk & 7) * 32 + (blk >> 3);
    const int mt = wl >> 2, nt = wl & 3;
    const int n0 = nt * 128, m0 = mt * 128;
    const int t = threadIdx.x, lane = t & 63, w = t >> 6;
    const int wm = w >> 1, wn = w & 1;
    const int quad = lane >> 4, l16 = lane & 15;

    const _Float16* Ab = Ah + ((size_t)mt * 8) * 8192 + w * 512 + lane * 8;
    const _Float16* Bb = Wt + (size_t)(4 + nt) * 8 * 8192 + w * 512 + lane * 8;

    v4f acc[4][4];
#pragma unroll
    for (int mi = 0; mi < 4; mi++)
#pragma unroll
        for (int ni = 0; ni < 4; ni++) acc[mi][ni] = (v4f)0.f;

#pragma unroll
    for (int i = 0; i < 4; i++) {
        gload16(Ab + i * 2048, &As[0][w * 512 + i * 2048]);
        gload16(Bb + i * 2048, &Bs[0][w * 512 + i * 2048]);
    }
    __syncthreads();

    int cur = 0;
    for (int kc = 0; kc < 8; ++kc) {
        const int nxt = cur ^ 1;
        if (kc + 1 < 8) {
#pragma unroll
            for (int i = 0; i < 4; i++) {
                gload16(Ab + (kc + 1) * 8192 + i * 2048, &As[nxt][w * 512 + i * 2048]);
                gload16(Bb + (kc + 1) * 8192 + i * 2048, &Bs[nxt][w * 512 + i * 2048]);
            }
        }

#pragma unroll
        for (int ks = 0; ks < 2; ++ks) {
            const int sxx = (ks * 32 + quad * 8) ^ ((l16 & 7) * 8);
            v8h af[4], bf[4];
#pragma unroll
            for (int mi = 0; mi < 4; mi++)
                af[mi] = *(const v8h*)&As[cur][(wm * 64 + mi * 16 + l16) * 64 + sxx];
#pragma unroll
            for (int ni = 0; ni < 4; ni++)
                bf[ni] = *(const v8h*)&Bs[cur][(wn * 64 + ni * 16 + l16) * 64 + sxx];
#pragma unroll
            for (int mi = 0; mi < 4; mi++)
#pragma unroll
                for (int ni = 0; ni < 4; ni++)
                    acc[mi][ni] = __builtin_amdgcn_mfma_f32_16x16x32_f16(af[mi], bf[ni], acc[mi][ni], 0, 0, 0);
        }
        __syncthreads();
        cur = nxt;
    }

#pragma unroll
    for (int mi = 0; mi < 4; mi++) {
        int mb = m0 + wm * 64 + mi * 16 + quad * 4;
#pragma unroll
        for (int ni = 0; ni < 4; ni++) {
            int n = n0 + wn * 64 + ni * 16 + l16;
            float bj = bo[n];
#pragma unroll
            for (int r = 0; r < 4; r++)
                out[(size_t)(mb + r) * 512 + n] = acc[mi][ni][r] + bj;
        }
    }
}

// ---------------------------------------------------------------------------
// R24 flash: R23 structure (single-barrier dbuf) + T5 setprio(1) around the
// QK and PV MFMA clusters. Mechanism (catalog T5, m191): waves from the 2
// independent co-resident blocks sit at different phases (QK/exp/PV); raising
// MFMA-phase wave priority lets the CU scheduler keep the matrix pipe fed
// while other-block waves run exp/staging VALU. Attn-verified +4-7%.
// Inner math verbatim. Pre-commit: flash >= 55 µs -> T5 null -> plateau.
// ---------------------------------------------------------------------------
__global__ __launch_bounds__(256) void flash_attn_f16(const _Float16* __restrict__ Qh,
                                                      const _Float16* __restrict__ Kh,
                                                      const _Float16* __restrict__ VT,
                                                      _Float16* __restrict__ Ah) {
    __shared__ _Float16 Ks[2][128 * 72];    // [key][d], pad 72
    __shared__ _Float16 Vs[2][64 * 136];    // [d][pos], pad 136

    const int t     = threadIdx.x;
    const int lane  = t & 63;
    const int w     = t >> 6;
    const int quad  = lane >> 4;
    const int l16   = lane & 15;
    // XCD-aware decode: 512 blocks, blk&7 = XCD, 4 (b,h) pairs + 16 q-blocks each
    const int blk = blockIdx.x;
    const int xcd = blk & 7, idx = blk >> 3;
    const int pid = xcd * 4 + (idx >> 4);   // 0..31
    const int qb  = idx & 15;
    const int b   = pid >> 3, h = pid & 7;
    const int q0  = qb * 128;

    const size_t base  = (size_t)b * S_ * D_ + (size_t)h * HD_;
    const size_t vbase = ((size_t)b * H_ + h) * HD_ * (size_t)S_;

    v8h qf[2][2];
#pragma unroll
    for (int nb = 0; nb < 2; nb++) {
        const _Float16* qrow = Qh + base + (size_t)(q0 + w * 32 + nb * 16 + l16) * D_;
        qf[nb][0] = *(const v8h*)(qrow + quad * 8);
        qf[nb][1] = *(const v8h*)(qrow + 32 + quad * 8);
    }

    v4f o[2][4];
#pragma unroll
    for (int nb = 0; nb < 2; nb++)
#pragma unroll
        for (int i = 0; i < 4; i++) o[nb][i] = (v4f)0.f;
    float l_lane[2] = {0.f, 0.f};

    v8h kv[4], vv[4];
#define LOADKV(kk)                                                             \
    do {                                                                       \
        _Pragma("unroll") for (int i = 0; i < 4; i++) {                        \
            int c = t + i * 256;                                               \
            kv[i] = *(const v8h*)(Kh + base + (size_t)((kk) + (c >> 3)) * D_ + (c & 7) * 8); \
            vv[i] = *(const v8h*)(VT + vbase + (size_t)(c >> 4) * S_ + (kk) + (c & 15) * 8); \
        }                                                                      \
    } while (0)

#define STOREKV(buf)                                                           \
    do {                                                                       \
        _Pragma("unroll") for (int i = 0; i < 4; i++) {                        \
            int c = t + i * 256;                                               \
            *(v8h*)&Ks[buf][(c >> 3) * 72 + (c & 7) * 8] = kv[i];              \
            *(v8h*)&Vs[buf][(c >> 4) * 136 + (c & 15) * 8] = vv[i];            \
        }                                                                      \
    } while (0)

    // Prologue: tile 0 -> buf 0; tile 1 -> regs.
    LOADKV(0);
    STOREKV(0);
    LOADKV(128);
    __syncthreads();

    int cur = 0;
    for (int kk0 = 0; kk0 < S_; kk0 += 128) {
        const int nxt = cur ^ 1;
        // Issue tile k+2 loads, then write tile k+1 (regs from last iter).
        if (kk0 + 128 < S_) {
            STOREKV(nxt);                       // waits vmcnt on k+1 loads (landed)
            if (kk0 + 256 < S_) LOADKV(kk0 + 256);
        }

#pragma unroll
        for (int hh = 0; hh < 2; hh++) {
            v4f sc[4][2];
#pragma unroll
            for (int mb = 0; mb < 4; mb++)
#pragma unroll
                for (int nb = 0; nb < 2; nb++) sc[mb][nb] = (v4f)0.f;
            __builtin_amdgcn_s_setprio(1);      // T5: QK MFMA cluster
#pragma unroll
            for (int ks = 0; ks < 2; ks++) {
#pragma unroll
                for (int mb = 0; mb < 4; mb++) {
                    v8h ak = *(const v8h*)&Ks[cur][(hh * 64 + mb * 16 + l16) * 72 + ks * 32 + quad * 8];
#pragma unroll
                    for (int nb = 0; nb < 2; nb++)
                        sc[mb][nb] = __builtin_amdgcn_mfma_f32_16x16x32_f16(ak, qf[nb][ks], sc[mb][nb], 0, 0, 0);
                }
            }
            __builtin_amdgcn_s_setprio(0);

            v4h pf[4][2];
#pragma unroll
            for (int nb = 0; nb < 2; nb++) {
#pragma unroll
                for (int mb = 0; mb < 4; mb++) {
                    v4f pv;
#pragma unroll
                    for (int r = 0; r < 4; r++) pv[r] = __builtin_amdgcn_exp2f(sc[mb][nb][r]);
                    pf[mb][nb] = __builtin_convertvector(pv, v4h);
                    l_lane[nb] += (pv[0] + pv[1]) + (pv[2] + pv[3]);
                }
            }

            __builtin_amdgcn_s_setprio(1);      // T5: PV MFMA cluster
#pragma unroll
            for (int p = 0; p < 2; p++) {
#pragma unroll
                for (int dblk = 0; dblk < 4; dblk++) {
                    v8h vf2 = *(const v8h*)&Vs[cur][(dblk * 16 + l16) * 136 + hh * 64 + p * 32 + quad * 8];
                    v4h vlo = __builtin_shufflevector(vf2, vf2, 0, 1, 2, 3);
                    v4h vhi = __builtin_shufflevector(vf2, vf2, 4, 5, 6, 7);
#pragma unroll
                    for (int nb = 0; nb < 2; nb++) {
                        o[nb][dblk] = __builtin_amdgcn_mfma_f32_16x16x16f16(vlo, pf[2 * p][nb], o[nb][dblk], 0, 0, 0);
                        o[nb][dblk] = __builtin_amdgcn_mfma_f32_16x16x16f16(vhi, pf[2 * p + 1][nb], o[nb][dblk], 0, 0, 0);
                    }
                }
            }
            __builtin_amdgcn_s_setprio(0);
        }
        __syncthreads();   // single barrier per tile
        cur = nxt;
    }
#undef LOADKV
#undef STOREKV

    // Epilogue: full-row l, normalize, write f16 blocked-swizzled Ah.
#pragma unroll
    for (int nb = 0; nb < 2; nb++) {
        float rs = l_lane[nb];
        rs += __shfl_xor(rs, 16);
        rs += __shfl_xor(rs, 32);
        float linv = __builtin_amdgcn_rcpf(rs);
        int r = w * 32 + nb * 16 + l16;
        _Float16* blkp = Ah + (((size_t)(b * 16 + qb)) * 8 + h) * 8192 + r * 64;
#pragma unroll
        for (int dblk = 0; dblk < 4; dblk++) {
            int s = dblk * 2 + (quad >> 1);
            v4h pk;
#pragma unroll
            for (int rr = 0; rr < 4; rr++) pk[rr] = (_Float16)(o[nb][dblk][rr] * linv);
            *(v4h*)&blkp[((s ^ (r & 7)) * 8) + (quad & 1) * 4] = pk;
        }
    }
}

extern "C" void kernel_launch(void* const* d_in, const int* in_sizes, int n_in,
                              void* d_out, int out_size, void* d_ws, size_t ws_size,
                              hipStream_t stream) {
    const float* query = (const float*)d_in[0];
    const float* key   = (const float*)d_in[1];
    const float* value = (const float*)d_in[2];
    const float* Wq    = (const float*)d_in[3];
    const float* bq    = (const float*)d_in[4];
    const float* Wo    = (const float*)d_in[5];
    const float* bo    = (const float*)d_in[6];
    float* out = (float*)d_out;

    _Float16* ws = (_Float16*)d_ws;
    _Float16* Qh = ws;                                   // [B,S,D] f16
    _Float16* Kh = ws + (size_t)SZ_;                     // [B,S,D] f16
    _Float16* VT = ws + 2 * (size_t)SZ_;                 // [B,H,HD,S] f16 (permuted)
    _Float16* Wt = ws + 3 * (size_t)SZ_;                 // 2x[4 nt][8 kc][128x64 swz] f16
    _Float16* Ah = ws + 3 * (size_t)SZ_ + 2 * (size_t)WSZ_;  // [mt64][kc8][128x64 swz] f16

    wtrans_kernel<<<dim3(8, 4, 2), 256, 0, stream>>>(Wq, Wo, Wt);
    proj_mfma<<<dim3(768), 256, 0, stream>>>(query, key, value, Wt, bq, Qh, Kh, VT);
    flash_attn_f16<<<dim3(512), 256, 0, stream>>>(Qh, Kh, VT, Ah);
    outproj_mfma<<<dim3(256), 256, 0, stream>>>(Ah, Wt, bo, out);
}

// Round 15
// 184.104 us; speedup vs baseline: 1.0266x; 1.0266x over previous
//
#include <hip/hip_runtime.h>
#include <math.h>

#define B_ 4
#define S_ 2048
#define D_ 512
#define H_ 8
#define HD_ 64
#define SZ_ (B_ * S_ * D_)
#define WSZ_ (D_ * D_)   // 262144
#define BSH_ (B_ * S_ * H_)

// 0.125 * log2(e): folds the 1/sqrt(64) score scale and exp->exp2 into Qh.
#define QSCALE_ 0.18033688011112042f

typedef _Float16 v4h __attribute__((ext_vector_type(4)));
typedef _Float16 v8h __attribute__((ext_vector_type(8)));
typedef float    v4f __attribute__((ext_vector_type(4)));

// Async global->LDS, 16B per lane. LDS dest must be wave-uniform base
// (HW adds lane*16); global source is per-lane.
__device__ __forceinline__ void gload16(const void* g, void* l) {
    __builtin_amdgcn_global_load_lds((__attribute__((address_space(1))) void*)g,
                                     (__attribute__((address_space(3))) void*)l,
                                     16, 0, 0);
}

__device__ __forceinline__ v8h pack8(v4f a, v4f b) {
    return __builtin_shufflevector(__builtin_convertvector(a, v4h),
                                   __builtin_convertvector(b, v4h),
                                   0, 1, 2, 3, 4, 5, 6, 7);
}

// ---------------------------------------------------------------------------
// W[k][n] fp32 -> 16KB swizzled f16 blocks, 128 n-rows x 64 k each.
// ---------------------------------------------------------------------------
__global__ __launch_bounds__(256) void wtrans_kernel(const float* __restrict__ Wq,
                                                     const float* __restrict__ Wo,
                                                     _Float16* __restrict__ Wt) {
    __shared__ float Ts[64][132];
    const int kc = blockIdx.x, nt = blockIdx.y, mat = blockIdx.z;
    const float* W = mat ? Wo : Wq;
    const int k0 = kc * 64, n0 = nt * 128;
    const int t = threadIdx.x;
#pragma unroll
    for (int i = 0; i < 8; i++) {
        int s2 = t + i * 256;
        int kk = s2 >> 5, nc = (s2 & 31) * 4;
        *(float4*)&Ts[kk][nc] = *(const float4*)&W[(size_t)(k0 + kk) * 512 + n0 + nc];
    }
    __syncthreads();
    _Float16* blk = Wt + (((size_t)mat * 4 + nt) * 8 + kc) * 8192;
#pragma unroll
    for (int i = 0; i < 4; i++) {
        int s2 = t + i * 256;
        int r = s2 >> 3, s = s2 & 7;
        int kl = (s ^ (r & 7)) * 8;
        v8h p;
#pragma unroll
        for (int j = 0; j < 8; j++) p[j] = (_Float16)Ts[kl + j][r];
        *(v8h*)&blk[r * 64 + s * 8] = p;
    }
}

// ---------------------------------------------------------------------------
// R20 proj (FROZEN): 2-phase single-barrier pipelined GEMM.
// ---------------------------------------------------------------------------
__global__ __launch_bounds__(256) void proj_mfma(const float* __restrict__ q,
                                                 const float* __restrict__ kin,
                                                 const float* __restrict__ v,
                                                 const _Float16* __restrict__ Wt,
                                                 const float* __restrict__ bq,
                                                 _Float16* __restrict__ Qh,
                                                 _Float16* __restrict__ Kh,
                                                 _Float16* __restrict__ VT) {
    __shared__ __align__(16) _Float16 As[2][8192];
    __shared__ __align__(16) _Float16 Bs[2][8192];
    const int blk = blockIdx.x;
    const int wl = (blk & 7) * 96 + (blk >> 3);
    const int z = wl >> 8;
    const int rem = wl & 255;
    const int mt = rem >> 2, nt = rem & 3;
    const int n0 = nt * 128, m0 = mt * 128;
    const float* X = (z == 0) ? q : ((z == 1) ? kin : v);
    const int t = threadIdx.x, lane = t & 63, w = t >> 6;
    const int wm = w >> 1, wn = w & 1;
    const int quad = lane >> 4, l16 = lane & 15;

    const float* Ap[4];
    int wofs[4];
#pragma unroll
    for (int i = 0; i < 4; i++) {
        int s2 = t + i * 256;
        int r = s2 >> 3, c = s2 & 7;
        Ap[i] = X + (size_t)(m0 + r) * 512 + c * 8;
        wofs[i] = r * 64 + ((c ^ (r & 7)) * 8);
    }
    const _Float16* Bb = Wt + ((size_t)nt * 8) * 8192 + w * 512 + lane * 8;

    v4f acc[4][4];
#pragma unroll
    for (int mi = 0; mi < 4; mi++)
#pragma unroll
        for (int ni = 0; ni < 4; ni++) acc[mi][ni] = (v4f)0.f;

    v4f a0[4], a1[4];
#pragma unroll
    for (int i = 0; i < 4; i++) {
        a0[i] = *(const v4f*)(Ap[i]);
        a1[i] = *(const v4f*)(Ap[i] + 4);
    }
#pragma unroll
    for (int i = 0; i < 4; i++) *(v8h*)&As[0][wofs[i]] = pack8(a0[i], a1[i]);
#pragma unroll
    for (int i = 0; i < 4; i++)
        gload16(Bb + i * 2048, &Bs[0][w * 512 + i * 2048]);
#pragma unroll
    for (int i = 0; i < 4; i++) {
        a0[i] = *(const v4f*)(Ap[i] + 64);
        a1[i] = *(const v4f*)(Ap[i] + 68);
    }
    __syncthreads();

    int cur = 0;
    for (int kc = 0; kc < 8; ++kc) {
        const int nxt = cur ^ 1;
        if (kc + 1 < 8) {
#pragma unroll
            for (int i = 0; i < 4; i++) *(v8h*)&As[nxt][wofs[i]] = pack8(a0[i], a1[i]);
#pragma unroll
            for (int i = 0; i < 4; i++)
                gload16(Bb + (kc + 1) * 8192 + i * 2048, &Bs[nxt][w * 512 + i * 2048]);
        }
        if (kc + 2 < 8) {
#pragma unroll
            for (int i = 0; i < 4; i++) {
                a0[i] = *(const v4f*)(Ap[i] + (kc + 2) * 64);
                a1[i] = *(const v4f*)(Ap[i] + (kc + 2) * 64 + 4);
            }
        }

#pragma unroll
        for (int ks = 0; ks < 2; ++ks) {
            const int sxx = (ks * 32 + quad * 8) ^ ((l16 & 7) * 8);
            v8h af[4], bf[4];
#pragma unroll
            for (int mi = 0; mi < 4; mi++)
                af[mi] = *(const v8h*)&As[cur][(wm * 64 + mi * 16 + l16) * 64 + sxx];
#pragma unroll
            for (int ni = 0; ni < 4; ni++)
                bf[ni] = *(const v8h*)&Bs[cur][(wn * 64 + ni * 16 + l16) * 64 + sxx];
#pragma unroll
            for (int mi = 0; mi < 4; mi++)
#pragma unroll
                for (int ni = 0; ni < 4; ni++)
                    acc[mi][ni] = __builtin_amdgcn_mfma_f32_16x16x32_f16(af[mi], bf[ni], acc[mi][ni], 0, 0, 0);
        }
        __syncthreads();
        cur = nxt;
    }

    if (z < 2) {
        _Float16* Y = z ? Kh : Qh;
        const float sc = z ? 1.f : QSCALE_;
#pragma unroll
        for (int mi = 0; mi < 4; mi++) {
            int mb = m0 + wm * 64 + mi * 16 + quad * 4;
#pragma unroll
            for (int ni = 0; ni < 4; ni++) {
                int n = n0 + wn * 64 + ni * 16 + l16;
                float bj = bq[n];
#pragma unroll
                for (int r = 0; r < 4; r++)
                    Y[(size_t)(mb + r) * 512 + n] = (_Float16)((acc[mi][ni][r] + bj) * sc);
            }
        }
    } else {
#pragma unroll
        for (int mi = 0; mi < 4; mi++) {
            int tile0 = (m0 & 2047) + wm * 64;
            int pos = tile0 + (mi >> 1) * 32 + quad * 8 + (mi & 1) * 4;
            int b = m0 >> 11;
#pragma unroll
            for (int ni = 0; ni < 4; ni++) {
                int n = n0 + wn * 64 + ni * 16 + l16;
                int h = n >> 6, dd = n & 63;
                float bj = bq[n];
                v4h pk;
#pragma unroll
                for (int r = 0; r < 4; r++) pk[r] = (_Float16)(acc[mi][ni][r] + bj);
                *(v4h*)&VT[(((size_t)b * H_ + h) * HD_ + dd) * S_ + pos] = pk;
            }
        }
    }
}

// ---------------------------------------------------------------------------
// R20 outproj (FROZEN): 2-phase single-barrier, both operands gload_lds dbuf.
// ---------------------------------------------------------------------------
__global__ __launch_bounds__(256) void outproj_mfma(const _Float16* __restrict__ Ah,
                                                    const _Float16* __restrict__ Wt,
                                                    const float* __restrict__ bo,
                                                    float* __restrict__ out) {
    __shared__ __align__(16) _Float16 As[2][8192];
    __shared__ __align__(16) _Float16 Bs[2][8192];
    const int blk = blockIdx.x;
    const int wl = (blk & 7) * 32 + (blk >> 3);
    const int mt = wl >> 2, nt = wl & 3;
    const int n0 = nt * 128, m0 = mt * 128;
    const int t = threadIdx.x, lane = t & 63, w = t >> 6;
    const int wm = w >> 1, wn = w & 1;
    const int quad = lane >> 4, l16 = lane & 15;

    const _Float16* Ab = Ah + ((size_t)mt * 8) * 8192 + w * 512 + lane * 8;
    const _Float16* Bb = Wt + (size_t)(4 + nt) * 8 * 8192 + w * 512 + lane * 8;

    v4f acc[4][4];
#pragma unroll
    for (int mi = 0; mi < 4; mi++)
#pragma unroll
        for (int ni = 0; ni < 4; ni++) acc[mi][ni] = (v4f)0.f;

#pragma unroll
    for (int i = 0; i < 4; i++) {
        gload16(Ab + i * 2048, &As[0][w * 512 + i * 2048]);
        gload16(Bb + i * 2048, &Bs[0][w * 512 + i * 2048]);
    }
    __syncthreads();

    int cur = 0;
    for (int kc = 0; kc < 8; ++kc) {
        const int nxt = cur ^ 1;
        if (kc + 1 < 8) {
#pragma unroll
            for (int i = 0; i < 4; i++) {
                gload16(Ab + (kc + 1) * 8192 + i * 2048, &As[nxt][w * 512 + i * 2048]);
                gload16(Bb + (kc + 1) * 8192 + i * 2048, &Bs[nxt][w * 512 + i * 2048]);
            }
        }

#pragma unroll
        for (int ks = 0; ks < 2; ++ks) {
            const int sxx = (ks * 32 + quad * 8) ^ ((l16 & 7) * 8);
            v8h af[4], bf[4];
#pragma unroll
            for (int mi = 0; mi < 4; mi++)
                af[mi] = *(const v8h*)&As[cur][(wm * 64 + mi * 16 + l16) * 64 + sxx];
#pragma unroll
            for (int ni = 0; ni < 4; ni++)
                bf[ni] = *(const v8h*)&Bs[cur][(wn * 64 + ni * 16 + l16) * 64 + sxx];
#pragma unroll
            for (int mi = 0; mi < 4; mi++)
#pragma unroll
                for (int ni = 0; ni < 4; ni++)
                    acc[mi][ni] = __builtin_amdgcn_mfma_f32_16x16x32_f16(af[mi], bf[ni], acc[mi][ni], 0, 0, 0);
        }
        __syncthreads();
        cur = nxt;
    }

#pragma unroll
    for (int mi = 0; mi < 4; mi++) {
        int mb = m0 + wm * 64 + mi * 16 + quad * 4;
#pragma unroll
        for (int ni = 0; ni < 4; ni++) {
            int n = n0 + wn * 64 + ni * 16 + l16;
            float bj = bo[n];
#pragma unroll
            for (int r = 0; r < 4; r++)
                out[(size_t)(mb + r) * 512 + n] = acc[mi][ni][r] + bj;
        }
    }
}

// ---------------------------------------------------------------------------
// R25 flash = R23 VERBATIM (best-known; setprio removed — R24 showed it
// perturbs regalloc 124->100 VGPR and regresses ~8 µs). Single-barrier
// double-buffered K/V (16 barrier drains/block), no split-K, Ah direct
// write, XCD grid, pad-72/136 LDS, QK 16x16x32, PV 16x16x16.
// Structural levers all falsified on this design: wave-count (R22),
// barriers (R23), conflicts (R16), occupancy (R15/R18), setprio (R24).
// ---------------------------------------------------------------------------
__global__ __launch_bounds__(256) void flash_attn_f16(const _Float16* __restrict__ Qh,
                                                      const _Float16* __restrict__ Kh,
                                                      const _Float16* __restrict__ VT,
                                                      _Float16* __restrict__ Ah) {
    __shared__ _Float16 Ks[2][128 * 72];    // [key][d], pad 72
    __shared__ _Float16 Vs[2][64 * 136];    // [d][pos], pad 136

    const int t     = threadIdx.x;
    const int lane  = t & 63;
    const int w     = t >> 6;
    const int quad  = lane >> 4;
    const int l16   = lane & 15;
    // XCD-aware decode: 512 blocks, blk&7 = XCD, 4 (b,h) pairs + 16 q-blocks each
    const int blk = blockIdx.x;
    const int xcd = blk & 7, idx = blk >> 3;
    const int pid = xcd * 4 + (idx >> 4);   // 0..31
    const int qb  = idx & 15;
    const int b   = pid >> 3, h = pid & 7;
    const int q0  = qb * 128;

    const size_t base  = (size_t)b * S_ * D_ + (size_t)h * HD_;
    const size_t vbase = ((size_t)b * H_ + h) * HD_ * (size_t)S_;

    v8h qf[2][2];
#pragma unroll
    for (int nb = 0; nb < 2; nb++) {
        const _Float16* qrow = Qh + base + (size_t)(q0 + w * 32 + nb * 16 + l16) * D_;
        qf[nb][0] = *(const v8h*)(qrow + quad * 8);
        qf[nb][1] = *(const v8h*)(qrow + 32 + quad * 8);
    }

    v4f o[2][4];
#pragma unroll
    for (int nb = 0; nb < 2; nb++)
#pragma unroll
        for (int i = 0; i < 4; i++) o[nb][i] = (v4f)0.f;
    float l_lane[2] = {0.f, 0.f};

    v8h kv[4], vv[4];
#define LOADKV(kk)                                                             \
    do {                                                                       \
        _Pragma("unroll") for (int i = 0; i < 4; i++) {                        \
            int c = t + i * 256;                                               \
            kv[i] = *(const v8h*)(Kh + base + (size_t)((kk) + (c >> 3)) * D_ + (c & 7) * 8); \
            vv[i] = *(const v8h*)(VT + vbase + (size_t)(c >> 4) * S_ + (kk) + (c & 15) * 8); \
        }                                                                      \
    } while (0)

#define STOREKV(buf)                                                           \
    do {                                                                       \
        _Pragma("unroll") for (int i = 0; i < 4; i++) {                        \
            int c = t + i * 256;                                               \
            *(v8h*)&Ks[buf][(c >> 3) * 72 + (c & 7) * 8] = kv[i];              \
            *(v8h*)&Vs[buf][(c >> 4) * 136 + (c & 15) * 8] = vv[i];            \
        }                                                                      \
    } while (0)

    // Prologue: tile 0 -> buf 0; tile 1 -> regs.
    LOADKV(0);
    STOREKV(0);
    LOADKV(128);
    __syncthreads();

    int cur = 0;
    for (int kk0 = 0; kk0 < S_; kk0 += 128) {
        const int nxt = cur ^ 1;
        // Issue tile k+2 loads, then write tile k+1 (regs from last iter).
        if (kk0 + 128 < S_) {
            STOREKV(nxt);                       // waits vmcnt on k+1 loads (landed)
            if (kk0 + 256 < S_) LOADKV(kk0 + 256);
        }

#pragma unroll
        for (int hh = 0; hh < 2; hh++) {
            v4f sc[4][2];
#pragma unroll
            for (int mb = 0; mb < 4; mb++)
#pragma unroll
                for (int nb = 0; nb < 2; nb++) sc[mb][nb] = (v4f)0.f;
#pragma unroll
            for (int ks = 0; ks < 2; ks++) {
#pragma unroll
                for (int mb = 0; mb < 4; mb++) {
                    v8h ak = *(const v8h*)&Ks[cur][(hh * 64 + mb * 16 + l16) * 72 + ks * 32 + quad * 8];
#pragma unroll
                    for (int nb = 0; nb < 2; nb++)
                        sc[mb][nb] = __builtin_amdgcn_mfma_f32_16x16x32_f16(ak, qf[nb][ks], sc[mb][nb], 0, 0, 0);
                }
            }

            v4h pf[4][2];
#pragma unroll
            for (int nb = 0; nb < 2; nb++) {
#pragma unroll
                for (int mb = 0; mb < 4; mb++) {
                    v4f pv;
#pragma unroll
                    for (int r = 0; r < 4; r++) pv[r] = __builtin_amdgcn_exp2f(sc[mb][nb][r]);
                    pf[mb][nb] = __builtin_convertvector(pv, v4h);
                    l_lane[nb] += (pv[0] + pv[1]) + (pv[2] + pv[3]);
                }
            }

#pragma unroll
            for (int p = 0; p < 2; p++) {
#pragma unroll
                for (int dblk = 0; dblk < 4; dblk++) {
                    v8h vf2 = *(const v8h*)&Vs[cur][(dblk * 16 + l16) * 136 + hh * 64 + p * 32 + quad * 8];
                    v4h vlo = __builtin_shufflevector(vf2, vf2, 0, 1, 2, 3);
                    v4h vhi = __builtin_shufflevector(vf2, vf2, 4, 5, 6, 7);
#pragma unroll
                    for (int nb = 0; nb < 2; nb++) {
                        o[nb][dblk] = __builtin_amdgcn_mfma_f32_16x16x16f16(vlo, pf[2 * p][nb], o[nb][dblk], 0, 0, 0);
                        o[nb][dblk] = __builtin_amdgcn_mfma_f32_16x16x16f16(vhi, pf[2 * p + 1][nb], o[nb][dblk], 0, 0, 0);
                    }
                }
            }
        }
        __syncthreads();   // single barrier per tile
        cur = nxt;
    }
#undef LOADKV
#undef STOREKV

    // Epilogue: full-row l, normalize, write f16 blocked-swizzled Ah.
#pragma unroll
    for (int nb = 0; nb < 2; nb++) {
        float rs = l_lane[nb];
        rs += __shfl_xor(rs, 16);
        rs += __shfl_xor(rs, 32);
        float linv = __builtin_amdgcn_rcpf(rs);
        int r = w * 32 + nb * 16 + l16;
        _Float16* blkp = Ah + (((size_t)(b * 16 + qb)) * 8 + h) * 8192 + r * 64;
#pragma unroll
        for (int dblk = 0; dblk < 4; dblk++) {
            int s = dblk * 2 + (quad >> 1);
            v4h pk;
#pragma unroll
            for (int rr = 0; rr < 4; rr++) pk[rr] = (_Float16)(o[nb][dblk][rr] * linv);
            *(v4h*)&blkp[((s ^ (r & 7)) * 8) + (quad & 1) * 4] = pk;
        }
    }
}

extern "C" void kernel_launch(void* const* d_in, const int* in_sizes, int n_in,
                              void* d_out, int out_size, void* d_ws, size_t ws_size,
                              hipStream_t stream) {
    const float* query = (const float*)d_in[0];
    const float* key   = (const float*)d_in[1];
    const float* value = (const float*)d_in[2];
    const float* Wq    = (const float*)d_in[3];
    const float* bq    = (const float*)d_in[4];
    const float* Wo    = (const float*)d_in[5];
    const float* bo    = (const float*)d_in[6];
    float* out = (float*)d_out;

    _Float16* ws = (_Float16*)d_ws;
    _Float16* Qh = ws;                                   // [B,S,D] f16
    _Float16* Kh = ws + (size_t)SZ_;                     // [B,S,D] f16
    _Float16* VT = ws + 2 * (size_t)SZ_;                 // [B,H,HD,S] f16 (permuted)
    _Float16* Wt = ws + 3 * (size_t)SZ_;                 // 2x[4 nt][8 kc][128x64 swz] f16
    _Float16* Ah = ws + 3 * (size_t)SZ_ + 2 * (size_t)WSZ_;  // [mt64][kc8][128x64 swz] f16

    wtrans_kernel<<<dim3(8, 4, 2), 256, 0, stream>>>(Wq, Wo, Wt);
    proj_mfma<<<dim3(768), 256, 0, stream>>>(query, key, value, Wt, bq, Qh, Kh, VT);
    flash_attn_f16<<<dim3(512), 256, 0, stream>>>(Qh, Kh, VT, Ah);
    outproj_mfma<<<dim3(256), 256, 0, stream>>>(Ah, Wt, bo, out);
}